// Round 16
// baseline (19.527 us; speedup 1.0000x reference)
//
#include <hip/hip_runtime.h>

#define HH 512
#define WW 512
#define NIMG 16
#define EPSF 1e-5f
#define INV81 (1.0f / 81.0f)

// lane l receives lane l-1's value; lane 0 -> 0  (wave_shr:1, bound_ctrl=1)
__device__ __forceinline__ float dpp_shr1(float x) {
    return __int_as_float(__builtin_amdgcn_update_dpp(
        0, __float_as_int(x), 0x138, 0xF, 0xF, true));
}
// lane l receives lane l+1's value; lane 63 -> 0  (wave_shl:1, bound_ctrl=1)
__device__ __forceinline__ float dpp_shl1(float x) {
    return __int_as_float(__builtin_amdgcn_update_dpp(
        0, __float_as_int(x), 0x130, 0xF, 0xF, true));
}

// Block = 8 waves (512 thr), one (image, 32-row strip). 24-slot LDS ring
// (96 KB), conflict-free float4 layout, DPP hbox, XCD swizzle, plain-store
// partials (R15). R16 change: ADJACENT-ROW PAIRING + INCREMENTAL vertical
// sums -- wave w computes rows {2w,2w+1} per step; row A+1 reuses row A's
// window via +new/-old (11 slot-reads per 2 rows vs 18) -> LDS-pipe traffic
// 36 -> 22 b128/output row, vertical-sum VALU 360 -> 220/row. Strip 32 also
// cuts the fetch halo 1.5x -> 1.25x. 256 blocks = exactly 1/CU.
__global__ __launch_bounds__(512, 2) void ncc_main(const float* __restrict__ Iin,
                                                   const float* __restrict__ Jin,
                                                   float* __restrict__ part) {
    __shared__ float4 ring4[24][2][128];  // 96 KB: [slot][img][A(0..63)|B(64..127)]
    __shared__ float wsum[8];

    const int tid  = threadIdx.x;
    const int lane = tid & 63;
    const int w    = tid >> 6;           // wave id 0..7
    const int xcd  = blockIdx.x & 7;     // HW round-robin XCD
    const int idx  = blockIdx.x >> 3;    // 0..31 within XCD
    const int n    = (xcd << 1) | (idx >> 4);   // image (2 per XCD = 4MB = L2)
    const int y0   = (idx & 15) << 5;           // strip base output row (32 rows)
    const int c0   = lane << 3;          // 8 cols per lane (global addressing)

    const float* Ib = Iin + (size_t)n * (HH * WW);
    const float* Jb = Jin + (size_t)n * (HH * WW);

    // rr = row - (y0-4), valid rr in [0,40); slot = rr mod 24
    auto gload = [&](int rr, float4& a0, float4& a1, float4& b0, float4& b1) {
        const int r = y0 - 4 + rr;
        if (r >= 0 && r < HH) {           // wave-uniform
            const float4* pI = (const float4*)(Ib + (size_t)r * WW + c0);
            const float4* pJ = (const float4*)(Jb + (size_t)r * WW + c0);
            a0 = pI[0]; a1 = pI[1]; b0 = pJ[0]; b1 = pJ[1];
        } else {
            a0 = a1 = b0 = b1 = make_float4(0.f, 0.f, 0.f, 0.f);
        }
    };
    auto swrite = [&](int rr, const float4& a0, const float4& a1,
                              const float4& b0, const float4& b1) {
        const int sl = rr < 24 ? rr : rr - 24;
        ring4[sl][0][lane]      = a0;     // A region: byte 16*lane
        ring4[sl][0][64 + lane] = a1;     // B region: byte 1024+16*lane
        ring4[sl][1][lane]      = b0;
        ring4[sl][1][64 + lane] = b1;
    };
    auto readslot = [&](int rr, float (&ai)[8], float (&bj)[8]) {
        const int sl = rr < 24 ? rr : rr - 24;
        const float4 i0 = ring4[sl][0][lane];
        const float4 i1 = ring4[sl][0][64 + lane];
        const float4 j0 = ring4[sl][1][lane];
        const float4 j1 = ring4[sl][1][64 + lane];
        ai[0]=i0.x; ai[1]=i0.y; ai[2]=i0.z; ai[3]=i0.w;
        ai[4]=i1.x; ai[5]=i1.y; ai[6]=i1.z; ai[7]=i1.w;
        bj[0]=j0.x; bj[1]=j0.y; bj[2]=j0.z; bj[3]=j0.w;
        bj[4]=j1.x; bj[5]=j1.y; bj[6]=j1.z; bj[7]=j1.w;
    };

    // Prologue: 24 rows rr=0..23 (y0-4 .. y0+19), 3 per wave.
    {
        float4 p0, p1, q0, q1;
        #pragma unroll
        for (int k = 0; k < 3; ++k) {
            gload(3 * w + k, p0, p1, q0, q1);
            swrite(3 * w + k, p0, p1, q0, q1);
        }
    }
    __syncthreads();                      // B1

    // Step-1 rows (rr 24+2w, 25+2w) issued now; land during step-0 compute.
    float4 na0, na1, nb0, nb1, ma0, ma1, mb0, mb1;
    gload(24 + 2 * w, na0, na1, nb0, nb1);
    gload(25 + 2 * w, ma0, ma1, mb0, mb1);

    auto hbox = [&](const float (&C)[8], float (&B)[8]) {
        float H[16];
        #pragma unroll
        for (int k = 0; k < 4; ++k) H[k] = dpp_shr1(C[4 + k]);   // lane-1 cols
        #pragma unroll
        for (int k = 0; k < 8; ++k) H[4 + k] = C[k];
        #pragma unroll
        for (int k = 0; k < 4; ++k) H[12 + k] = dpp_shl1(C[k]);  // lane+1 cols
        float s = ((H[0] + H[1]) + (H[2] + H[3])) + ((H[4] + H[5]) + (H[6] + H[7])) + H[8];
        B[0] = s;
        #pragma unroll
        for (int i = 1; i < 8; ++i) { s += H[i + 8] - H[i - 1]; B[i] = s; }
    };

    float local = 0.f;

    // box + cc for current window sums
    auto ccrow = [&](const float (&SI)[8], const float (&SJ)[8],
                     const float (&SI2)[8], const float (&SJ2)[8],
                     const float (&SIJ)[8]) {
        float BI[8], BJ[8], BI2[8], BJ2[8], BIJ[8];
        hbox(SI, BI); hbox(SJ, BJ); hbox(SI2, BI2); hbox(SJ2, BJ2); hbox(SIJ, BIJ);
        #pragma unroll
        for (int c = 0; c < 8; ++c) {
            const float tI = BI[c] * INV81;
            const float tJ = BJ[c] * INV81;
            const float cross = fmaf(-tI, BJ[c], BIJ[c]);
            const float Iv    = fmaf(-tI, BI[c], BI2[c]);
            const float Jv    = fmaf(-tJ, BJ[c], BJ2[c]);
            const float den   = fmaf(Iv, Jv, EPSF);
            local = fmaf(cross * cross, __builtin_amdgcn_rcpf(den), local);
        }
    };

    // Two adjacent output rows starting at window-base rrA:
    // row A = windows rr rrA..rrA+8 (full sum), row A+1 incremental.
    auto dopair = [&](int rrA) {
        float SI[8], SJ[8], SI2[8], SJ2[8], SIJ[8];
        #pragma unroll
        for (int c = 0; c < 8; ++c) { SI[c]=0.f; SJ[c]=0.f; SI2[c]=0.f; SJ2[c]=0.f; SIJ[c]=0.f; }
        float ai[8], bj[8];
        #pragma unroll
        for (int k = 0; k < 9; ++k) {
            readslot(rrA + k, ai, bj);
            #pragma unroll
            for (int c = 0; c < 8; ++c) {
                SI[c] += ai[c];  SJ[c] += bj[c];
                SI2[c] = fmaf(ai[c], ai[c], SI2[c]);
                SJ2[c] = fmaf(bj[c], bj[c], SJ2[c]);
                SIJ[c] = fmaf(ai[c], bj[c], SIJ[c]);
            }
        }
        ccrow(SI, SJ, SI2, SJ2, SIJ);     // row A

        readslot(rrA + 9, ai, bj);         // + new bottom row
        #pragma unroll
        for (int c = 0; c < 8; ++c) {
            SI[c] += ai[c];  SJ[c] += bj[c];
            SI2[c] = fmaf(ai[c], ai[c], SI2[c]);
            SJ2[c] = fmaf(bj[c], bj[c], SJ2[c]);
            SIJ[c] = fmaf(ai[c], bj[c], SIJ[c]);
        }
        readslot(rrA, ai, bj);             // - old top row
        #pragma unroll
        for (int c = 0; c < 8; ++c) {
            SI[c] -= ai[c];  SJ[c] -= bj[c];
            SI2[c] = fmaf(-ai[c], ai[c], SI2[c]);
            SJ2[c] = fmaf(-bj[c], bj[c], SJ2[c]);
            SIJ[c] = fmaf(-ai[c], bj[c], SIJ[c]);
        }
        ccrow(SI, SJ, SI2, SJ2, SIJ);     // row A+1
    };

    // Step 0: output rows y0+2w, y0+2w+1 (windows rr 2w..2w+9 <= 23, resident).
    dopair(2 * w);
    __syncthreads();                      // B2: all step-0 reads done
    swrite(24 + 2 * w, na0, na1, nb0, nb1);   // slots 2w, 2w+1: dead rows
    swrite(25 + 2 * w, ma0, ma1, mb0, mb1);
    __syncthreads();                      // B3: rows rr 24..39 visible
    // Step 1: output rows y0+16+2w, +17+2w (windows rr 16+2w..25+2w <= 39).
    dopair(16 + 2 * w);

    // wave reduction -> block reduction -> one plain store per block
    #pragma unroll
    for (int off = 32; off > 0; off >>= 1) local += __shfl_down(local, off);
    if (lane == 0) wsum[w] = local;
    __syncthreads();
    if (tid == 0) {
        float b = 0.f;
        #pragma unroll
        for (int k = 0; k < 8; ++k) b += wsum[k];
        part[blockIdx.x] = b;             // distinct address per block
    }
}

// 1 block, 256 threads: reduce 256 partials, write the scalar output.
__global__ __launch_bounds__(256) void ncc_final(const float* __restrict__ part,
                                                 float* __restrict__ out) {
    __shared__ float s[4];
    const int tid  = threadIdx.x;
    const int lane = tid & 63;
    const int w    = tid >> 6;
    float v = part[tid];
    #pragma unroll
    for (int off = 32; off > 0; off >>= 1) v += __shfl_down(v, off);
    if (lane == 0) s[w] = v;
    __syncthreads();
    if (tid == 0) {
        float t = (s[0] + s[1]) + (s[2] + s[3]);
        out[0] = 1.0f - t * (1.0f / (float)((size_t)NIMG * HH * WW));
    }
}

extern "C" void kernel_launch(void* const* d_in, const int* in_sizes, int n_in,
                              void* d_out, int out_size, void* d_ws, size_t ws_size,
                              hipStream_t stream) {
    const float* I = (const float*)d_in[0];
    const float* J = (const float*)d_in[1];
    float* out  = (float*)d_out;
    float* part = (float*)d_ws;          // 256 floats, fully rewritten each call

    // 256 blocks = 16 images x 16 strips of 32 rows = exactly 1 block/CU.
    ncc_main<<<256, 512, 0, stream>>>(I, J, part);
    ncc_final<<<1, 256, 0, stream>>>(part, out);
}

// Round 17
// 15.925 us; speedup vs baseline: 1.2262x; 1.2262x over previous
//
#include <hip/hip_runtime.h>

#define HH 512
#define WW 512
#define NIMG 16
#define EPSF 1e-5f
#define INV81 (1.0f / 81.0f)

// lane l receives lane l-1's value; lane 0 -> 0  (wave_shr:1, bound_ctrl=1)
__device__ __forceinline__ float dpp_shr1(float x) {
    return __int_as_float(__builtin_amdgcn_update_dpp(
        0, __float_as_int(x), 0x138, 0xF, 0xF, true));
}
// lane l receives lane l+1's value; lane 63 -> 0  (wave_shl:1, bound_ctrl=1)
__device__ __forceinline__ float dpp_shl1(float x) {
    return __int_as_float(__builtin_amdgcn_update_dpp(
        0, __float_as_int(x), 0x130, 0xF, 0xF, true));
}

// R17: single-phase blocks. 1024 blocks x 8 waves, one (image, 8-row strip)
// each. 16-slot LDS buffer (64 KB -> 2 blocks/CU, 4 waves/SIMD = R15's
// proven occupancy): each wave loads 2 rows -> ONE barrier -> each wave
// computes one output row -> reduce -> plain store part[bid]. No mid-kernel
// barriers, no held prefetch regs; cross-block overlap (2 resident, 4
// generations/CU) replaces in-kernel phase pipelining. Conflict-free
// float4 LDS layout + DPP hbox + XCD swizzle + no atomics (R15 wins kept).
__global__ __launch_bounds__(512, 4) void ncc_main(const float* __restrict__ Iin,
                                                   const float* __restrict__ Jin,
                                                   float* __restrict__ part) {
    __shared__ float4 ring4[16][2][128];  // 64 KB: [slot][img][A(0..63)|B(64..127)]
    __shared__ float wsum[8];

    const int tid  = threadIdx.x;
    const int lane = tid & 63;
    const int w    = tid >> 6;           // wave id 0..7
    const int xcd  = blockIdx.x & 7;     // HW round-robin XCD
    const int idx  = blockIdx.x >> 3;    // 0..127 within XCD
    const int n    = (xcd << 1) | (idx >> 6);   // image (2 per XCD = L2-sized)
    const int y0   = (idx & 63) << 3;           // strip base output row (8 rows)
    const int c0   = lane << 3;          // 8 cols per lane (global addressing)

    const float* Ib = Iin + (size_t)n * (HH * WW);
    const float* Jb = Jin + (size_t)n * (HH * WW);

    // rr = row - (y0-4), rr in [0,16)
    auto gload = [&](int rr, float4& a0, float4& a1, float4& b0, float4& b1) {
        const int r = y0 - 4 + rr;
        if (r >= 0 && r < HH) {           // wave-uniform
            const float4* pI = (const float4*)(Ib + (size_t)r * WW + c0);
            const float4* pJ = (const float4*)(Jb + (size_t)r * WW + c0);
            a0 = pI[0]; a1 = pI[1]; b0 = pJ[0]; b1 = pJ[1];
        } else {
            a0 = a1 = b0 = b1 = make_float4(0.f, 0.f, 0.f, 0.f);
        }
    };
    auto swrite = [&](int rr, const float4& a0, const float4& a1,
                              const float4& b0, const float4& b1) {
        ring4[rr][0][lane]      = a0;     // A region: byte 16*lane
        ring4[rr][0][64 + lane] = a1;     // B region: byte 1024+16*lane
        ring4[rr][1][lane]      = b0;
        ring4[rr][1][64 + lane] = b1;
    };

    // Prologue: 16 rows (rr 0..15), 2 per wave, independent; one barrier.
    {
        float4 p0, p1, q0, q1, r0, r1, s0, s1;
        gload(2 * w,     p0, p1, q0, q1);
        gload(2 * w + 1, r0, r1, s0, s1);
        swrite(2 * w,     p0, p1, q0, q1);
        swrite(2 * w + 1, r0, r1, s0, s1);
    }
    __syncthreads();                      // the only barrier before reduce

    auto hbox = [&](const float (&C)[8], float (&B)[8]) {
        float H[16];
        #pragma unroll
        for (int k = 0; k < 4; ++k) H[k] = dpp_shr1(C[4 + k]);   // lane-1 cols
        #pragma unroll
        for (int k = 0; k < 8; ++k) H[4 + k] = C[k];
        #pragma unroll
        for (int k = 0; k < 4; ++k) H[12 + k] = dpp_shl1(C[k]);  // lane+1 cols
        float s = ((H[0] + H[1]) + (H[2] + H[3])) + ((H[4] + H[5]) + (H[6] + H[7])) + H[8];
        B[0] = s;
        #pragma unroll
        for (int i = 1; i < 8; ++i) { s += H[i + 8] - H[i - 1]; B[i] = s; }
    };

    float local = 0.f;

    // This wave's output row: window rr = w .. w+8 (all resident).
    {
        float SI[8], SJ[8], SI2[8], SJ2[8], SIJ[8];
        #pragma unroll
        for (int c = 0; c < 8; ++c) { SI[c]=0.f; SJ[c]=0.f; SI2[c]=0.f; SJ2[c]=0.f; SIJ[c]=0.f; }
        #pragma unroll
        for (int k = 0; k < 9; ++k) {
            const int sl = w + k;
            const float4 i0 = ring4[sl][0][lane];
            const float4 i1 = ring4[sl][0][64 + lane];
            const float4 j0 = ring4[sl][1][lane];
            const float4 j1 = ring4[sl][1][64 + lane];
            const float ai[8] = {i0.x, i0.y, i0.z, i0.w, i1.x, i1.y, i1.z, i1.w};
            const float bj[8] = {j0.x, j0.y, j0.z, j0.w, j1.x, j1.y, j1.z, j1.w};
            #pragma unroll
            for (int c = 0; c < 8; ++c) {
                SI[c] += ai[c];  SJ[c] += bj[c];
                SI2[c] = fmaf(ai[c], ai[c], SI2[c]);
                SJ2[c] = fmaf(bj[c], bj[c], SJ2[c]);
                SIJ[c] = fmaf(ai[c], bj[c], SIJ[c]);
            }
        }
        float BI[8], BJ[8], BI2[8], BJ2[8], BIJ[8];
        hbox(SI, BI); hbox(SJ, BJ); hbox(SI2, BI2); hbox(SJ2, BJ2); hbox(SIJ, BIJ);
        #pragma unroll
        for (int c = 0; c < 8; ++c) {
            const float tI = BI[c] * INV81;
            const float tJ = BJ[c] * INV81;
            const float cross = fmaf(-tI, BJ[c], BIJ[c]);
            const float Iv    = fmaf(-tI, BI[c], BI2[c]);
            const float Jv    = fmaf(-tJ, BJ[c], BJ2[c]);
            const float den   = fmaf(Iv, Jv, EPSF);
            local = fmaf(cross * cross, __builtin_amdgcn_rcpf(den), local);
        }
    }

    // wave reduction -> block reduction -> one plain store per block
    #pragma unroll
    for (int off = 32; off > 0; off >>= 1) local += __shfl_down(local, off);
    if (lane == 0) wsum[w] = local;
    __syncthreads();
    if (tid == 0) {
        float b = 0.f;
        #pragma unroll
        for (int k = 0; k < 8; ++k) b += wsum[k];
        part[blockIdx.x] = b;             // distinct address per block
    }
}

// 1 block, 1024 threads: reduce 1024 partials, write the scalar output.
__global__ __launch_bounds__(1024) void ncc_final(const float* __restrict__ part,
                                                  float* __restrict__ out) {
    __shared__ float s[16];
    const int tid  = threadIdx.x;
    const int lane = tid & 63;
    const int w    = tid >> 6;
    float v = part[tid];
    #pragma unroll
    for (int off = 32; off > 0; off >>= 1) v += __shfl_down(v, off);
    if (lane == 0) s[w] = v;
    __syncthreads();
    if (tid == 0) {
        float t = 0.f;
        #pragma unroll
        for (int k = 0; k < 16; ++k) t += s[k];
        out[0] = 1.0f - t * (1.0f / (float)((size_t)NIMG * HH * WW));
    }
}

extern "C" void kernel_launch(void* const* d_in, const int* in_sizes, int n_in,
                              void* d_out, int out_size, void* d_ws, size_t ws_size,
                              hipStream_t stream) {
    const float* I = (const float*)d_in[0];
    const float* J = (const float*)d_in[1];
    float* out  = (float*)d_out;
    float* part = (float*)d_ws;          // 1024 floats, fully rewritten each call

    // 1024 blocks = 16 images x 64 strips of 8 rows; 8 waves/block;
    // 64 KB LDS -> 2 resident/CU (4 waves/SIMD), 4 generations/CU overlap.
    ncc_main<<<1024, 512, 0, stream>>>(I, J, part);
    ncc_final<<<1, 1024, 0, stream>>>(part, out);
}